// Round 1
// baseline (1413.376 us; speedup 1.0000x reference)
//
#include <hip/hip_runtime.h>
#include <hip/hip_fp16.h>

// AGCRN cell on MI355X. Precision: fp16 MFMA (16x16x32) with fp32 accum everywhere;
// fp32 softmax/sigmoid/tanh/epilogues. Threshold is 0.1 absmax -> fp16 (2^-11 rel)
// gives ~4x margin over bf16. Workspace use ~148 MB.

#define B_  64
#define N_  2048
#define D_  16
#define CO_ 64
#define CC_ 128   // concat channels (in+out)

typedef _Float16 f16x8 __attribute__((ext_vector_type(8)));
typedef float    f32x4 __attribute__((ext_vector_type(4)));

// ---------------------------------------------------------------------------
// A = softmax(relu(E E^T)) row-wise, stored fp16. One block per row.
__global__ __launch_bounds__(256)
void k_softmaxA(const float* __restrict__ E, __half* __restrict__ A) {
  const int n = blockIdx.x, t = threadIdx.x;
  __shared__ float row[N_];
  __shared__ float red[4];
  const float4* en4 = reinterpret_cast<const float4*>(E + n * D_);
  const float4 e0 = en4[0], e1 = en4[1], e2 = en4[2], e3 = en4[3];
  float lmax = 0.f;  // relu => scores >= 0, diag >= 0
  for (int m = t; m < N_; m += 256) {
    const float4* em4 = reinterpret_cast<const float4*>(E + m * D_);
    const float4 f0 = em4[0], f1 = em4[1], f2 = em4[2], f3 = em4[3];
    float d = e0.x*f0.x + e0.y*f0.y + e0.z*f0.z + e0.w*f0.w
            + e1.x*f1.x + e1.y*f1.y + e1.z*f1.z + e1.w*f1.w
            + e2.x*f2.x + e2.y*f2.y + e2.z*f2.z + e2.w*f2.w
            + e3.x*f3.x + e3.y*f3.y + e3.z*f3.z + e3.w*f3.w;
    d = fmaxf(d, 0.f);
    row[m] = d;
    lmax = fmaxf(lmax, d);
  }
  #pragma unroll
  for (int off = 32; off > 0; off >>= 1) lmax = fmaxf(lmax, __shfl_down(lmax, off));
  __syncthreads();
  if ((t & 63) == 0) red[t >> 6] = lmax;
  __syncthreads();
  const float gmax = fmaxf(fmaxf(red[0], red[1]), fmaxf(red[2], red[3]));
  float lsum = 0.f;
  for (int m = t; m < N_; m += 256) {
    float v = __expf(row[m] - gmax);
    row[m] = v;
    lsum += v;
  }
  #pragma unroll
  for (int off = 32; off > 0; off >>= 1) lsum += __shfl_down(lsum, off);
  __syncthreads();  // everyone finished reading red[] for gmax
  if ((t & 63) == 0) red[t >> 6] = lsum;
  __syncthreads();
  const float rinv = 1.f / (red[0] + red[1] + red[2] + red[3]);
  for (int m = t; m < N_; m += 256)
    A[(long)n * N_ + m] = __float2half(row[m] * rinv);
}

// ---------------------------------------------------------------------------
// Generic f16 GEMM: C = op(A @ B). A:[M x K] lda, B:[K x N] ldb, C ldc.
// Tile 128x128, BK=32, 256 threads (4 waves, each 64x64 = 4x4 frags of 16x16x32).
// MODE 0: C=v (fp16). MODE 1: C = 2v - I (fp16) for the Chebyshev support.
// blockIdx.z batches B/C via strides (A shared across z).
template <int MODE>
__global__ __launch_bounds__(256)
void k_gemm(const __half* __restrict__ Ag, const __half* __restrict__ Bg,
            __half* __restrict__ Cg, int K, int lda, int ldb, int ldc,
            long sB, long sC) {
  const int m0 = blockIdx.x * 128;
  const int n0 = blockIdx.y * 128;
  Bg += (long)blockIdx.z * sB;
  Cg += (long)blockIdx.z * sC;
  // rows padded to 40 halves (80 B) => even quad-bank spread for ds_read_b128
  __shared__ __half As[128][40];
  __shared__ __half Bs[128][40];
  const int t = threadIdx.x, lane = t & 63, wid = t >> 6;
  const int wm = (wid & 1) * 64, wn = (wid >> 1) * 64;
  f32x4 acc[4][4] = {};
  const int ar = t >> 1, aseg = t & 1;        // A staging: 16 halves per thread
  const int bc = t & 127, bkg = (t >> 7) * 8; // B staging: col + k-group

  for (int kt = 0; kt < K; kt += 32) {
    // stage A tile [128 x 32], row-major (k-contiguous)
    {
      const uint4* asrc = reinterpret_cast<const uint4*>(
          Ag + (long)(m0 + ar) * lda + kt + aseg * 16);
      uint4 av0 = asrc[0], av1 = asrc[1];
      *reinterpret_cast<uint4*>(&As[ar][aseg * 16])     = av0;
      *reinterpret_cast<uint4*>(&As[ar][aseg * 16 + 8]) = av1;
    }
    // stage B tile transposed: Bs[col][k] (k-contiguous for B fragments)
    #pragma unroll
    for (int it = 0; it < 2; ++it) {
      const int kk = bkg + it * 16;  // 0,8,16,24
      const __half* bsrc = Bg + (long)(kt + kk) * ldb + n0 + bc;
      ushort h[8];
      #pragma unroll
      for (int j = 0; j < 8; ++j) h[j] = __half_as_ushort(bsrc[(long)j * ldb]);
      uint4 pk;
      pk.x = (uint)h[0] | ((uint)h[1] << 16);
      pk.y = (uint)h[2] | ((uint)h[3] << 16);
      pk.z = (uint)h[4] | ((uint)h[5] << 16);
      pk.w = (uint)h[6] | ((uint)h[7] << 16);
      *reinterpret_cast<uint4*>(&Bs[bc][kk]) = pk;
    }
    __syncthreads();
    f16x8 af[4], bf[4];
    #pragma unroll
    for (int i = 0; i < 4; ++i) {
      af[i] = *reinterpret_cast<const f16x8*>(&As[wm + i * 16 + (lane & 15)][(lane >> 4) * 8]);
      bf[i] = *reinterpret_cast<const f16x8*>(&Bs[wn + i * 16 + (lane & 15)][(lane >> 4) * 8]);
    }
    #pragma unroll
    for (int i = 0; i < 4; ++i)
      #pragma unroll
      for (int j = 0; j < 4; ++j)
        acc[i][j] = __builtin_amdgcn_mfma_f32_16x16x32_f16(af[i], bf[j], acc[i][j], 0, 0, 0);
    __syncthreads();
  }
  // epilogue: D[row=(lane>>4)*4+r, col=lane&15]
  const int cr = (lane >> 4) * 4, ccol = lane & 15;
  #pragma unroll
  for (int i = 0; i < 4; ++i)
    #pragma unroll
    for (int j = 0; j < 4; ++j) {
      const int gr = m0 + wm + i * 16 + cr;
      const int gc = n0 + wn + j * 16 + ccol;
      #pragma unroll
      for (int r = 0; r < 4; ++r) {
        float v = acc[i][j][r];
        if (MODE == 1) v = 2.f * v - ((gr + r) == gc ? 1.f : 0.f);
        Cg[(long)(gr + r) * ldc + gc] = __float2half(v);
      }
    }
}

// ---------------------------------------------------------------------------
// XH[b][n][0:64]=X, [64:128]=H  (fp32 -> fp16)
__global__ __launch_bounds__(256)
void k_build_xh(const float* __restrict__ X, const float* __restrict__ H,
                __half* __restrict__ XH) {
  const long i = (long)blockIdx.x * 256 + threadIdx.x;  // quad id: B*N*32
  const long bn = i >> 5;
  const int  q  = (int)(i & 31);
  const float* src = (q < 16 ? X : H) + bn * 64 + (q & 15) * 4;
  const float4 v = *reinterpret_cast<const float4*>(src);
  ushort4 h;
  h.x = __half_as_ushort(__float2half(v.x));
  h.y = __half_as_ushort(__float2half(v.y));
  h.z = __half_as_ushort(__float2half(v.z));
  h.w = __half_as_ushort(__float2half(v.w));
  *reinterpret_cast<ushort4*>(XH + bn * CC_ + q * 4) = h;
}

// fp32 -> fp16 cast (pools), 4 elems/thread
__global__ __launch_bounds__(256)
void k_cast_f16(const float* __restrict__ src, __half* __restrict__ dst, int nquads) {
  const int i = blockIdx.x * 256 + threadIdx.x;
  if (i >= nquads) return;
  const float4 v = reinterpret_cast<const float4*>(src)[i];
  ushort4 h;
  h.x = __half_as_ushort(__float2half(v.x));
  h.y = __half_as_ushort(__float2half(v.y));
  h.z = __half_as_ushort(__float2half(v.z));
  h.w = __half_as_ushort(__float2half(v.w));
  *reinterpret_cast<ushort4*>(dst + i * 4) = h;
}

// bias[n][o] = sum_d E[n][d] * pool[d][o]
__global__ __launch_bounds__(256)
void k_bias(const float* __restrict__ E, const float* __restrict__ pool,
            float* __restrict__ bias, int O) {
  const int idx = blockIdx.x * 256 + threadIdx.x;
  const int n = idx / O, o = idx - n * O;
  float s = 0.f;
  #pragma unroll
  for (int d = 0; d < D_; ++d) s += E[n * D_ + d] * pool[d * O + o];
  bias[idx] = s;
}

// ---------------------------------------------------------------------------
// Gate: per node n, ZR[64b x 128o] = sum_k XGk @ Wk  (K=3*128), then sigmoid.
// Z -> XH[b][n][64+o] = Z*H (in-place: buffer becomes C), R -> Rbuf fp32.
__global__ __launch_bounds__(256)
void k_gate(const __half* __restrict__ XH, const __half* __restrict__ G1,
            const __half* __restrict__ G2, const __half* __restrict__ poolg,
            const float* __restrict__ E, const float* __restrict__ bg,
            const float* __restrict__ H, __half* __restrict__ XHw,
            float* __restrict__ R) {
  const int n = blockIdx.x, t = threadIdx.x, lane = t & 63, wid = t >> 6;
  __shared__ __half Ws[128][136];  // [o][i], k-contiguous, 272B rows (quad-bank even)
  __shared__ __half Ds[64][136];   // [b][i]
  __shared__ float es[D_];
  if (t < D_) es[t] = E[n * D_ + t];
  __syncthreads();
  f32x4 acc[4][2] = {};
  const __half* srcs[3] = {XH, G1, G2};
  #pragma unroll
  for (int kc = 0; kc < 3; ++kc) {
    {  // stage data tile: XGkc[:, n, :]  (64 x 128)
      const int b = t & 63, seg = t >> 6;
      const uint4* s = reinterpret_cast<const uint4*>(
          srcs[kc] + ((long)b * N_ + n) * CC_ + seg * 32);
      uint4 v0 = s[0], v1 = s[1], v2 = s[2], v3 = s[3];
      uint4* d = reinterpret_cast<uint4*>(&Ds[b][seg * 32]);
      d[0] = v0; d[1] = v1; d[2] = v2; d[3] = v3;
    }
    // stage W chunk: Ws[o][i] = sum_d E[n,d] * pool[d][kc][i][o]
    const __half* pk = poolg + (long)kc * 128 * 128;
    for (int p = t; p < 64 * 128; p += 256) {
      const int o2 = p & 63, i = p >> 6;
      float w0 = 0.f, w1 = 0.f;
      #pragma unroll
      for (int d = 0; d < D_; ++d) {
        const __half2 h2 = *reinterpret_cast<const __half2*>(
            pk + (long)d * 3 * 128 * 128 + i * 128 + o2 * 2);
        const float e = es[d];
        w0 += e * __half2float(h2.x);
        w1 += e * __half2float(h2.y);
      }
      Ws[o2 * 2][i]     = __float2half(w0);
      Ws[o2 * 2 + 1][i] = __float2half(w1);
    }
    __syncthreads();
    #pragma unroll
    for (int ks = 0; ks < 4; ++ks) {
      f16x8 a[4], bf[2];
      #pragma unroll
      for (int i = 0; i < 4; ++i)
        a[i] = *reinterpret_cast<const f16x8*>(&Ds[i * 16 + (lane & 15)][ks * 32 + (lane >> 4) * 8]);
      #pragma unroll
      for (int j = 0; j < 2; ++j)
        bf[j] = *reinterpret_cast<const f16x8*>(&Ws[wid * 32 + j * 16 + (lane & 15)][ks * 32 + (lane >> 4) * 8]);
      #pragma unroll
      for (int i = 0; i < 4; ++i)
        #pragma unroll
        for (int j = 0; j < 2; ++j)
          acc[i][j] = __builtin_amdgcn_mfma_f32_16x16x32_f16(a[i], bf[j], acc[i][j], 0, 0, 0);
    }
    __syncthreads();
  }
  const int cr = (lane >> 4) * 4, co = lane & 15;
  #pragma unroll
  for (int i = 0; i < 4; ++i)
    #pragma unroll
    for (int j = 0; j < 2; ++j) {
      const int o = wid * 32 + j * 16 + co;
      const float bv = bg[n * 128 + o];
      #pragma unroll
      for (int r = 0; r < 4; ++r) {
        const int b = i * 16 + cr + r;
        const float v = acc[i][j][r] + bv;
        const float s = 1.f / (1.f + __expf(-v));
        const long base = ((long)b * N_ + n) * CO_ + (o & 63);
        if (o < 64) {
          XHw[((long)b * N_ + n) * CC_ + 64 + o] = __float2half(s * H[base]);
        } else {
          R[base] = s;
        }
      }
    }
}

// ---------------------------------------------------------------------------
// Update: per node n, HCpre[64b x 64o] = sum_k XGk @ Wk; out = R*H + (1-R)*tanh(.)
__global__ __launch_bounds__(256)
void k_update(const __half* __restrict__ C, const __half* __restrict__ G1,
              const __half* __restrict__ G2, const __half* __restrict__ poolu,
              const float* __restrict__ E, const float* __restrict__ bu,
              const float* __restrict__ H, const float* __restrict__ R,
              float* __restrict__ out) {
  const int n = blockIdx.x, t = threadIdx.x, lane = t & 63, wid = t >> 6;
  __shared__ __half Ws[64][136];
  __shared__ __half Ds[64][136];
  __shared__ float es[D_];
  if (t < D_) es[t] = E[n * D_ + t];
  __syncthreads();
  f32x4 acc[4] = {};
  const __half* srcs[3] = {C, G1, G2};
  #pragma unroll
  for (int kc = 0; kc < 3; ++kc) {
    {
      const int b = t & 63, seg = t >> 6;
      const uint4* s = reinterpret_cast<const uint4*>(
          srcs[kc] + ((long)b * N_ + n) * CC_ + seg * 32);
      uint4 v0 = s[0], v1 = s[1], v2 = s[2], v3 = s[3];
      uint4* d = reinterpret_cast<uint4*>(&Ds[b][seg * 32]);
      d[0] = v0; d[1] = v1; d[2] = v2; d[3] = v3;
    }
    const __half* pk = poolu + (long)kc * 128 * 64;
    for (int p = t; p < 32 * 128; p += 256) {
      const int o2 = p & 31, i = p >> 5;
      float w0 = 0.f, w1 = 0.f;
      #pragma unroll
      for (int d = 0; d < D_; ++d) {
        const __half2 h2 = *reinterpret_cast<const __half2*>(
            pk + (long)d * 3 * 128 * 64 + i * 64 + o2 * 2);
        const float e = es[d];
        w0 += e * __half2float(h2.x);
        w1 += e * __half2float(h2.y);
      }
      Ws[o2 * 2][i]     = __float2half(w0);
      Ws[o2 * 2 + 1][i] = __float2half(w1);
    }
    __syncthreads();
    #pragma unroll
    for (int ks = 0; ks < 4; ++ks) {
      f16x8 a[4], bf;
      #pragma unroll
      for (int i = 0; i < 4; ++i)
        a[i] = *reinterpret_cast<const f16x8*>(&Ds[i * 16 + (lane & 15)][ks * 32 + (lane >> 4) * 8]);
      bf = *reinterpret_cast<const f16x8*>(&Ws[wid * 16 + (lane & 15)][ks * 32 + (lane >> 4) * 8]);
      #pragma unroll
      for (int i = 0; i < 4; ++i)
        acc[i] = __builtin_amdgcn_mfma_f32_16x16x32_f16(a[i], bf, acc[i], 0, 0, 0);
    }
    __syncthreads();
  }
  const int cr = (lane >> 4) * 4, co = lane & 15;
  const int o = wid * 16 + co;
  const float bv = bu[n * 64 + o];
  #pragma unroll
  for (int i = 0; i < 4; ++i)
    #pragma unroll
    for (int r = 0; r < 4; ++r) {
      const int b = i * 16 + cr + r;
      const long idx = ((long)b * N_ + n) * CO_ + o;
      const float hc = tanhf(acc[i][r] + bv);
      const float rr = R[idx];
      out[idx] = rr * H[idx] + (1.f - rr) * hc;
    }
}

// ---------------------------------------------------------------------------
extern "C" void kernel_launch(void* const* d_in, const int* in_sizes, int n_in,
                              void* d_out, int out_size, void* d_ws, size_t ws_size,
                              hipStream_t stream) {
  const float* X  = (const float*)d_in[0];
  const float* E  = (const float*)d_in[1];
  const float* H  = (const float*)d_in[2];
  const float* gp = (const float*)d_in[3];  // [16][3][128][128]
  const float* gb = (const float*)d_in[4];  // [16][128]
  const float* up = (const float*)d_in[5];  // [16][3][128][64]
  const float* ub = (const float*)d_in[6];  // [16][64]
  float* out = (float*)d_out;

  size_t off = 0;
  auto alloc = [&](size_t bytes) {
    void* p = (char*)d_ws + off;
    off += (bytes + 255) & ~(size_t)255;
    return p;
  };
  __half* A16  = (__half*)alloc((size_t)N_ * N_ * 2);        // 8.4 MB
  __half* S16  = (__half*)alloc((size_t)N_ * N_ * 2);        // 8.4 MB
  __half* XH   = (__half*)alloc((size_t)B_ * N_ * CC_ * 2);  // 33.6 MB (becomes C)
  __half* G1   = (__half*)alloc((size_t)B_ * N_ * CC_ * 2);  // 33.6 MB
  __half* G2   = (__half*)alloc((size_t)B_ * N_ * CC_ * 2);  // 33.6 MB
  float*  Rbuf = (float*)alloc((size_t)B_ * N_ * CO_ * 4);   // 33.6 MB
  __half* pg   = (__half*)alloc((size_t)D_ * 3 * 128 * 128 * 2);
  __half* pu   = (__half*)alloc((size_t)D_ * 3 * 128 * 64 * 2);
  float*  bg   = (float*)alloc((size_t)N_ * 128 * 4);
  float*  bu   = (float*)alloc((size_t)N_ * 64 * 4);
  (void)ws_size;  // total ~148 MB

  const long sXH = (long)N_ * CC_;  // per-batch stride in halves

  k_cast_f16<<<768, 256, 0, stream>>>(gp, pg, 196608);
  k_cast_f16<<<384, 256, 0, stream>>>(up, pu, 98304);
  k_bias<<<1024, 256, 0, stream>>>(E, gb, bg, 128);
  k_bias<<<512, 256, 0, stream>>>(E, ub, bu, 64);
  k_softmaxA<<<N_, 256, 0, stream>>>(E, A16);
  // S2 = 2*A@A - I
  k_gemm<1><<<dim3(16, 16, 1), 256, 0, stream>>>(A16, A16, S16, N_, N_, N_, N_, 0, 0);
  k_build_xh<<<16384, 256, 0, stream>>>(X, H, XH);
  // gate graph propagation
  k_gemm<0><<<dim3(16, 1, B_), 256, 0, stream>>>(A16, XH, G1, N_, N_, CC_, CC_, sXH, sXH);
  k_gemm<0><<<dim3(16, 1, B_), 256, 0, stream>>>(S16, XH, G2, N_, N_, CC_, CC_, sXH, sXH);
  k_gate<<<N_, 256, 0, stream>>>(XH, G1, G2, pg, E, bg, H, XH, Rbuf);
  // update graph propagation (XH now holds C = [X, Z*H])
  k_gemm<0><<<dim3(16, 1, B_), 256, 0, stream>>>(A16, XH, G1, N_, N_, CC_, CC_, sXH, sXH);
  k_gemm<0><<<dim3(16, 1, B_), 256, 0, stream>>>(S16, XH, G2, N_, N_, CC_, CC_, sXH, sXH);
  k_update<<<N_, 256, 0, stream>>>(XH, G1, G2, pu, E, bu, H, Rbuf, out);
}